// Round 5
// baseline (625.714 us; speedup 1.0000x reference)
//
#include <hip/hip_runtime.h>

// Problem constants (from reference)
#define Bsz 16
#define Cc  256
#define Ll  4096
#define Pp  100
#define Qq  20
#define PQ  (Pp * Qq)     // 2000

// Tiling: block = 256 threads = 4 waves; lane owns 4 consecutive l (float4).
// Block covers LTILE=1024 l's and GP=10 p's -> per (p,q) row the block writes
// 4 KB CONTIGUOUS (4 waves x 1 KB adjacent).
#define LTILE 1024
#define NLT   (Ll / LTILE)   // 4
#define GP    10
#define NPG   (Pp / GP)      // 10

// native vector type (also valid for plain vector stores)
typedef float f32x4 __attribute__((ext_vector_type(4)));

// ---------------------------------------------------------------------------
// NUMERICS CONTRACT (bit-exact vs numpy fp32 reference, validated R2/R4):
//   a[b,p,l]: chain c=0..255 of a = fmaf(X[b,c,l], proj[p,c], a)      [fp32]
//   thr[p,q] = fadd(mn, fmul(fsub(mx,mn), fdiv(q+1, 21)))             [fp32,
//              separate roundings, no contraction]
//   cdf = popcount/4096 (exact dyadic fp32; atomic order irrelevant)
//
// R5 A/B: NT stores -> NORMAL cached stores. R4's NT path ran writes at
// ~2.2 TB/s effective; the harness fill hits 6.3 TB/s through L2 on the same
// buffer. Single-variable test of the L2-write-aggregation theory.
// ---------------------------------------------------------------------------
__global__ __launch_bounds__(256) void csf_main(
    const float* __restrict__ X,
    const float* __restrict__ proj,
    const float* __restrict__ mn,
    const float* __restrict__ mx,
    float* __restrict__ cdf,       // d_out[0 .. B*P*Q), zeroed before launch
    float* __restrict__ set_out) { // d_out + B*P*Q, [B][P*Q][L]
    const int lt  = blockIdx.x;                 // 0..NLT-1
    const int pg  = blockIdx.y;                 // 0..NPG-1
    const int b   = blockIdx.z;                 // 0..Bsz-1
    const int tid = threadIdx.x;
    const int l0  = lt * LTILE + tid * 4;       // 4 consecutive l per lane
    const int p0  = __builtin_amdgcn_readfirstlane(pg * GP);  // wave-uniform

    const float* Xb = X + (size_t)b * Cc * Ll + l0;  // c-th element block at +c*Ll

    float acc[GP][4];
#pragma unroll
    for (int i = 0; i < GP; i++)
#pragma unroll
        for (int k = 0; k < 4; k++) acc[i][k] = 0.0f;

    // fp32 FMA chains, c strictly ascending per accumulator (numpy order).
    // proj index is wave-uniform -> scalar loads; x is a 16B coalesced load.
#pragma unroll 4
    for (int c = 0; c < Cc; c++) {
        const f32x4 x = *(const f32x4*)(Xb + (size_t)c * Ll);
#pragma unroll
        for (int i = 0; i < GP; i++) {
            const float w = proj[(size_t)(p0 + i) * Cc + c];
            acc[i][0] = __builtin_fmaf(x.x, w, acc[i][0]);
            acc[i][1] = __builtin_fmaf(x.y, w, acc[i][1]);
            acc[i][2] = __builtin_fmaf(x.z, w, acc[i][2]);
            acc[i][3] = __builtin_fmaf(x.w, w, acc[i][3]);
        }
    }

    // fracs: fl((q+1)/21), IEEE division — same as np.arange/np.float32(21)
    float fr[Qq];
#pragma unroll
    for (int q = 0; q < Qq; q++) fr[q] = __fdiv_rn((float)(q + 1), 21.0f);

    float* ob = set_out + (size_t)b * PQ * Ll + l0;   // + (p*Q+q)*Ll
    const bool lane0 = ((tid & 63) == 0);

#pragma unroll 1
    for (int i = 0; i < GP; i++) {
        const int p = p0 + i;
        const float mnp = mn[p];
        const float mxp = mx[p];
        const float d = __fsub_rn(mxp, mnp);          // fl(mx-mn)
#pragma unroll
        for (int q = 0; q < Qq; q++) {
            // fl(mn + fl(d*frac)) — separate roundings, no FMA contraction
            const float thr = __fadd_rn(mnp, __fmul_rn(d, fr[q]));
            const bool b0 = acc[i][0] < thr;
            const bool b1 = acc[i][1] < thr;
            const bool b2 = acc[i][2] < thr;
            const bool b3 = acc[i][3] < thr;
            f32x4 o;
            o.x = b0 ? 1.0f : 0.0f;
            o.y = b1 ? 1.0f : 0.0f;
            o.z = b2 ? 1.0f : 0.0f;
            o.w = b3 ? 1.0f : 0.0f;
            // NORMAL cached store (L2 write aggregation) — R5's single change
            *(f32x4*)(ob + (size_t)(p * Qq + q) * Ll) = o;
            // per-wave count: 4 ballots (one per sub-l bit)
            const int cnt = __popcll(__ballot(b0)) + __popcll(__ballot(b1))
                          + __popcll(__ballot(b2)) + __popcll(__ballot(b3));
            if (lane0) {
                // exact: every term is a multiple of 2^-12, sums are dyadic <=1
                atomicAdd(&cdf[(size_t)b * PQ + p * Qq + q],
                          (float)cnt * (1.0f / (float)Ll));
            }
        }
    }
}

// ---------------------------------------------------------------------------
extern "C" void kernel_launch(void* const* d_in, const int* in_sizes, int n_in,
                              void* d_out, int out_size, void* d_ws, size_t ws_size,
                              hipStream_t stream) {
    const float* X    = (const float*)d_in[0];   // [B,C,L]
    const float* proj = (const float*)d_in[1];   // [P,C]
    const float* mn   = (const float*)d_in[2];   // [P]
    const float* mx   = (const float*)d_in[3];   // [P]

    float* cdf     = (float*)d_out;              // [B, P*Q]
    float* set_out = cdf + (size_t)Bsz * PQ;     // [B, P*Q, L]

    // zero cdf for atomic accumulation (128 KB, ~2 us)
    (void)hipMemsetAsync(cdf, 0, (size_t)Bsz * PQ * sizeof(float), stream);

    dim3 grid(NLT, NPG, Bsz);
    csf_main<<<grid, 256, 0, stream>>>(X, proj, mn, mx, cdf, set_out);
}

// Round 6
// 622.799 us; speedup vs baseline: 1.0047x; 1.0047x over previous
//
#include <hip/hip_runtime.h>

// Problem constants (from reference)
#define Bsz 16
#define Cc  256
#define Ll  4096
#define Pp  100
#define Qq  20
#define PQ  (Pp * Qq)     // 2000

// R6 tiling: grid (NLT=16, B=16) = 256 blocks = exactly 1 per CU.
// Block = 256 threads = 4 waves. Each wave handles 25 p's over the SAME
// 256-wide l-tile (lane owns 4 consecutive l -> 1 KB contiguous per wave
// store). All 4 waves load the same X rows -> HBM reads X ONCE (64 MB total);
// waves 2..4 hit L1/L2. NT stores keep the 524 MB write stream out of L2/L3
// (R4 vs R5 A/B: NT 603 vs cached 626).
#define LTILE 256
#define NLT   (Ll / LTILE)   // 16
#define PPW   25             // p's per wave

typedef float f32x4 __attribute__((ext_vector_type(4)));

// ---------------------------------------------------------------------------
// NUMERICS CONTRACT (bit-exact vs numpy fp32 reference, validated R2/R4/R5):
//   a[b,p,l]: chain c=0..255 of a = fmaf(X[b,c,l], proj[p,c], a)      [fp32]
//   thr[p,q] = fadd(mn, fmul(fsub(mx,mn), fdiv(q+1, 21)))             [fp32,
//              separate roundings, no contraction]
//   cdf = popcount/4096 (exact dyadic fp32; atomic order irrelevant)
// ---------------------------------------------------------------------------
__global__ __launch_bounds__(256) void csf_main(
    const float* __restrict__ X,
    const float* __restrict__ proj,
    const float* __restrict__ mn,
    const float* __restrict__ mx,
    float* __restrict__ cdf,       // d_out[0 .. B*P*Q), zeroed before launch
    float* __restrict__ set_out) { // d_out + B*P*Q, [B][P*Q][L]
    const int lt   = blockIdx.x;                // 0..NLT-1
    const int b    = blockIdx.y;                // 0..Bsz-1
    const int tid  = threadIdx.x;
    const int lane = tid & 63;
    const int p0   = __builtin_amdgcn_readfirstlane((tid >> 6) * PPW); // 0,25,50,75
    const int l0   = lt * LTILE + lane * 4;     // 4 consecutive l per lane

    const float* Xb = X + (size_t)b * Cc * Ll + l0;  // c-th element at +c*Ll
    const float* pj = proj + (size_t)p0 * Cc;        // pj[i*Cc + c], wave-uniform

    float acc[PPW][4];
#pragma unroll
    for (int i = 0; i < PPW; i++)
#pragma unroll
        for (int k = 0; k < 4; k++) acc[i][k] = 0.0f;

    // fp32 FMA chains, c strictly ascending per accumulator (numpy order).
    // proj index wave-uniform -> s_load; x is a 16 B coalesced load (1 KB/wave,
    // identical across the block's 4 waves -> one HBM fetch, rest L1/L2).
#pragma unroll 4
    for (int c = 0; c < Cc; c++) {
        const f32x4 x = *(const f32x4*)(Xb + (size_t)c * Ll);
#pragma unroll
        for (int i = 0; i < PPW; i++) {
            const float w = pj[(size_t)i * Cc + c];
            acc[i][0] = __builtin_fmaf(x.x, w, acc[i][0]);
            acc[i][1] = __builtin_fmaf(x.y, w, acc[i][1]);
            acc[i][2] = __builtin_fmaf(x.z, w, acc[i][2]);
            acc[i][3] = __builtin_fmaf(x.w, w, acc[i][3]);
        }
    }

    // fracs: fl((q+1)/21), IEEE division — same as np.arange/np.float32(21)
    float fr[Qq];
#pragma unroll
    for (int q = 0; q < Qq; q++) fr[q] = __fdiv_rn((float)(q + 1), 21.0f);

    float* ob = set_out + (size_t)b * PQ * Ll + l0;   // + (p*Q+q)*Ll
    const bool lane0 = (lane == 0);

#pragma unroll 1
    for (int i = 0; i < PPW; i++) {
        const int p = p0 + i;
        const float mnp = mn[p];
        const float mxp = mx[p];
        const float d = __fsub_rn(mxp, mnp);          // fl(mx-mn)
#pragma unroll
        for (int q = 0; q < Qq; q++) {
            // fl(mn + fl(d*frac)) — separate roundings, no FMA contraction
            const float thr = __fadd_rn(mnp, __fmul_rn(d, fr[q]));
            const bool b0 = acc[i][0] < thr;
            const bool b1 = acc[i][1] < thr;
            const bool b2 = acc[i][2] < thr;
            const bool b3 = acc[i][3] < thr;
            f32x4 o;
            o.x = b0 ? 1.0f : 0.0f;
            o.y = b1 ? 1.0f : 0.0f;
            o.z = b2 ? 1.0f : 0.0f;
            o.w = b3 ? 1.0f : 0.0f;
            // NT: streaming output, never re-read; keeps X resident in L2/L3
            __builtin_nontemporal_store(o, (f32x4*)(ob + (size_t)(p * Qq + q) * Ll));
            // per-wave count over this wave's 256 l's
            const int cnt = __popcll(__ballot(b0)) + __popcll(__ballot(b1))
                          + __popcll(__ballot(b2)) + __popcll(__ballot(b3));
            if (lane0) {
                // exact: every term is a multiple of 2^-12, sums are dyadic <=1
                atomicAdd(&cdf[(size_t)b * PQ + p * Qq + q],
                          (float)cnt * (1.0f / (float)Ll));
            }
        }
    }
}

// ---------------------------------------------------------------------------
extern "C" void kernel_launch(void* const* d_in, const int* in_sizes, int n_in,
                              void* d_out, int out_size, void* d_ws, size_t ws_size,
                              hipStream_t stream) {
    const float* X    = (const float*)d_in[0];   // [B,C,L]
    const float* proj = (const float*)d_in[1];   // [P,C]
    const float* mn   = (const float*)d_in[2];   // [P]
    const float* mx   = (const float*)d_in[3];   // [P]

    float* cdf     = (float*)d_out;              // [B, P*Q]
    float* set_out = cdf + (size_t)Bsz * PQ;     // [B, P*Q, L]

    // zero cdf for atomic accumulation (128 KB, ~2 us)
    (void)hipMemsetAsync(cdf, 0, (size_t)Bsz * PQ * sizeof(float), stream);

    dim3 grid(NLT, Bsz);
    csf_main<<<grid, 256, 0, stream>>>(X, proj, mn, mx, cdf, set_out);
}